// Round 1
// 438.434 us; speedup vs baseline: 1.0105x; 1.0105x over previous
//
#include <hip/hip_runtime.h>
#include <math.h>

#define H 1024
#define V 50257
#define L 4096
#define NB_ATTN 256                       // L / 16 rows per attn block
#define ROWS_PER_LOGB 32                  // 4 waves * 8 rows
#define LOGITS_BLOCKS ((V + ROWS_PER_LOGB - 1) / ROWS_PER_LOGB)   // 1571

__device__ __forceinline__ float wave_sum(float v) {
    #pragma unroll
    for (int off = 32; off; off >>= 1) v += __shfl_down(v, off);
    return v;
}

// online log-sum-exp merge: (m,s) <- merge((m,s),(m2,s2)), guarded for -inf
__device__ __forceinline__ void lse_merge(float& m, float& s, float m2, float s2) {
    if (m2 == -INFINITY) return;
    if (m == -INFINITY) { m = m2; s = s2; return; }
    float nm = fmaxf(m, m2);
    s = s * expf(m - nm) + s2 * expf(m2 - nm);
    m = nm;
}

// 1) fused scores + block-local softmax + context partials.
//    Block b owns rows [16b, 16b+16). Wave w computes e for row 16b+w.
//    Then block-local m_b, p = exp(e - m_b), s_b; column-partial
//    cpart[b][j] = sum_l p_l * h_all[l][j] (rows are L2-hot from phase A).
__global__ __launch_bounds__(1024) void k_attn(
    const float* __restrict__ h_all, const float* __restrict__ s_prev,
    const float* __restrict__ align_W, const float* __restrict__ align_b,
    float* __restrict__ p_ws, float2* __restrict__ pairs,
    float* __restrict__ cpart) {
    __shared__ float sh_e[16];
    __shared__ float sh_p[16];
    int tid = threadIdx.x, wave = tid >> 6, lane = tid & 63;
    int b = blockIdx.x;
    int l = b * 16 + wave;
    const float* hrow = h_all + (size_t)l * H;
    const float* Wh = align_W;
    const float* Ws = align_W + H;
    float acc = 0.f;
    #pragma unroll
    for (int it = 0; it < 4; ++it) {
        int k = it * 256 + lane * 4;
        float4 h4 = *(const float4*)(hrow + k);
        float4 w4 = *(const float4*)(Wh + k);
        float4 s4 = *(const float4*)(s_prev + k);
        float4 v4 = *(const float4*)(Ws + k);
        acc += h4.x * w4.x + h4.y * w4.y + h4.z * w4.z + h4.w * w4.w;
        acc += s4.x * v4.x + s4.y * v4.y + s4.z * v4.z + s4.w * v4.w;
    }
    acc = wave_sum(acc);
    if (lane == 0) sh_e[wave] = acc + align_b[0];
    __syncthreads();
    float m_b = sh_e[0];
    #pragma unroll
    for (int i = 1; i < 16; ++i) m_b = fmaxf(m_b, sh_e[i]);
    if (tid < 16) {
        float p = expf(sh_e[tid] - m_b);
        sh_p[tid] = p;
        p_ws[b * 16 + tid] = p;
    }
    __syncthreads();
    if (tid == 0) {
        float s_b = 0.f;
        #pragma unroll
        for (int i = 0; i < 16; ++i) s_b += sh_p[i];
        pairs[b] = make_float2(m_b, s_b);
    }
    // per-column context partial: thread j = tid (coalesced, rows L2-hot)
    float cacc = 0.f;
    #pragma unroll
    for (int i = 0; i < 16; ++i)
        cacc += sh_p[i] * h_all[(size_t)(b * 16 + i) * H + tid];
    cpart[(size_t)b * H + tid] = cacc;
}

// 2) merge: global (M,S) from 256 pairs (redundant per block, L2-hot);
//    write a slice; reduce cpart columns -> c. Block b: rows [16b,16b+16),
//    columns [4b, 4b+4).
__global__ __launch_bounds__(1024) void k_merge(
    const float2* __restrict__ pairs, const float* __restrict__ p_ws,
    const float* __restrict__ cpart, float* __restrict__ a_out,
    float* __restrict__ c) {
    __shared__ float shm[16], shs[16];
    __shared__ float shMS[2];
    __shared__ float shc4[16];
    int tid = threadIdx.x, wave = tid >> 6, lane = tid & 63;
    float m = -INFINITY, s = 0.f;
    if (tid < NB_ATTN) { float2 pr = pairs[tid]; m = pr.x; s = pr.y; }
    #pragma unroll
    for (int off = 32; off; off >>= 1) {
        float m2 = __shfl_down(m, off);
        float s2 = __shfl_down(s, off);
        lse_merge(m, s, m2, s2);
    }
    if (lane == 0) { shm[wave] = m; shs[wave] = s; }
    __syncthreads();
    if (tid == 0) {
        float M = shm[0], S = shs[0];
        for (int w = 1; w < 16; ++w) lse_merge(M, S, shm[w], shs[w]);
        shMS[0] = M; shMS[1] = S;
    }
    __syncthreads();
    float M = shMS[0];
    float invS = 1.f / shMS[1];
    // attention-weight output for this block's 16 rows
    if (tid < 16) {
        float scale = expf(pairs[blockIdx.x].x - M) * invS;
        a_out[blockIdx.x * 16 + tid] = p_ws[blockIdx.x * 16 + tid] * scale;
    }
    // c columns: col = 4*b + (tid>>8), partial index r = tid&255
    int cl = tid >> 8;
    int r  = tid & 255;
    int col = blockIdx.x * 4 + cl;
    float w_r = expf(pairs[r].x - M);
    float val = w_r * cpart[(size_t)r * H + col];
    val = wave_sum(val);
    if (lane == 0) shc4[wave] = val;
    __syncthreads();
    if (tid < 4) {
        float sum = shc4[tid * 4] + shc4[tid * 4 + 1] + shc4[tid * 4 + 2] + shc4[tid * 4 + 3];
        c[blockIdx.x * 4 + tid] = sum * invS;
    }
}

// 3) x[i] = new_W[i,:] · [emb ‖ c] + new_b[i]   (wave per row, dot over 2048)
__global__ void k_xvec(const float* __restrict__ new_W, const float* __restrict__ new_b,
                       const float* __restrict__ emb_W, const int* __restrict__ y,
                       const float* __restrict__ c, float* __restrict__ x) {
    int wave = threadIdx.x >> 6, lane = threadIdx.x & 63;
    int i = blockIdx.x * 4 + wave;
    const float* row = new_W + (size_t)i * (2 * H);
    const float* emb = emb_W + (size_t)y[0] * H;
    float acc = 0.f;
    #pragma unroll
    for (int it = 0; it < 8; ++it) {
        int k = it * 256 + lane * 4;
        float4 w4 = *(const float4*)(row + k);
        float4 v4 = (k < H) ? *(const float4*)(emb + k) : *(const float4*)(c + (k - H));
        acc += w4.x * v4.x + w4.y * v4.y + w4.z * v4.z + w4.w * v4.w;
    }
    acc = wave_sum(acc);
    if (lane == 0) x[i] = acc + new_b[i];
}

// 4) fused GRU: block per output i, 6 waves = 6 row-dots, thread 0 applies gates
__global__ void k_gru(const float* __restrict__ W_ih, const float* __restrict__ b_ih,
                      const float* __restrict__ W_hh, const float* __restrict__ b_hh,
                      const float* __restrict__ x, const float* __restrict__ s_prev,
                      float* __restrict__ h_ws, float* __restrict__ h_out) {
    __shared__ float dots[6];
    int wave = threadIdx.x >> 6, lane = threadIdx.x & 63;
    int i = blockIdx.x;
    int g = wave % 3;
    const float* row;
    const float* vec;
    if (wave < 3) { row = W_ih + (size_t)(g * H + i) * H; vec = x; }
    else          { row = W_hh + (size_t)(g * H + i) * H; vec = s_prev; }
    float acc = 0.f;
    #pragma unroll
    for (int it = 0; it < 4; ++it) {
        int k = it * 256 + lane * 4;
        float4 w4 = *(const float4*)(row + k);
        float4 v4 = *(const float4*)(vec + k);
        acc += w4.x * v4.x + w4.y * v4.y + w4.z * v4.z + w4.w * v4.w;
    }
    acc = wave_sum(acc);
    if (lane == 0) dots[wave] = acc;
    __syncthreads();
    if (threadIdx.x == 0) {
        float ir  = dots[0] + b_ih[i];
        float iz  = dots[1] + b_ih[H + i];
        float in_ = dots[2] + b_ih[2 * H + i];
        float hr  = dots[3] + b_hh[i];
        float hz  = dots[4] + b_hh[H + i];
        float hn  = dots[5] + b_hh[2 * H + i];
        float r = 1.f / (1.f + expf(-(ir + hr)));
        float z = 1.f / (1.f + expf(-(iz + hz)));
        float n = tanhf(in_ + r * hn);
        float h = (1.f - z) * n + z * s_prev[i];
        h_ws[i]  = h;
        h_out[i] = h;
    }
}

// 5) logits GEMV: 8 rows per wave, interleaved loads for 8-way MLP;
//    per-block online (m,s) pair for LSE
__global__ __launch_bounds__(256, 4) void k_logits(
    const float* __restrict__ out_W, const float* __restrict__ out_b,
    const float* __restrict__ h, float* __restrict__ logits,
    float2* __restrict__ pairs) {
    __shared__ __align__(16) float sh_h[H];
    __shared__ float2 wpair[4];
    int tid = threadIdx.x, wave = tid >> 6, lane = tid & 63;
    ((float4*)sh_h)[tid] = ((const float4*)h)[tid];
    __syncthreads();
    int v0 = blockIdx.x * ROWS_PER_LOGB + wave * 8;
    const float* base = out_W + (size_t)v0 * H;
    float acc[8] = {0.f, 0.f, 0.f, 0.f, 0.f, 0.f, 0.f, 0.f};
    if (v0 + 8 <= V) {
        #pragma unroll
        for (int it = 0; it < 4; ++it) {
            int k = it * 256 + lane * 4;
            float4 h4 = *(const float4*)(sh_h + k);
            #pragma unroll
            for (int r = 0; r < 8; ++r) {
                float4 w4 = *(const float4*)(base + (size_t)r * H + k);
                acc[r] += w4.x * h4.x + w4.y * h4.y + w4.z * h4.z + w4.w * h4.w;
            }
        }
    } else {
        for (int r = 0; r < 8; ++r) {
            if (v0 + r >= V) break;
            const float* rowp = base + (size_t)r * H;
            #pragma unroll
            for (int it = 0; it < 4; ++it) {
                int k = it * 256 + lane * 4;
                float4 h4 = *(const float4*)(sh_h + k);
                float4 w4 = *(const float4*)(rowp + k);
                acc[r] += w4.x * h4.x + w4.y * h4.y + w4.z * h4.z + w4.w * h4.w;
            }
        }
    }
    float m = -INFINITY, s = 0.f;
    #pragma unroll
    for (int r = 0; r < 8; ++r) {
        float red = wave_sum(acc[r]);
        if (lane == 0 && v0 + r < V) {
            float logit = red + out_b[v0 + r];
            logits[v0 + r] = logit;
            lse_merge(m, s, logit, 1.0f);
        }
    }
    if (lane == 0) wpair[wave] = make_float2(m, s);
    __syncthreads();
    if (tid == 0) {
        float M = wpair[0].x, S = wpair[0].y;
        for (int w = 1; w < 4; ++w) lse_merge(M, S, wpair[w].x, wpair[w].y);
        pairs[blockIdx.x] = make_float2(M, S);
    }
}

// 6) fused combine + finalize: each block redundantly reduces all pairs
//    (12.5 KB, L2-hot) then normalizes its 256-logit slice in place.
__global__ void k_final(const float2* __restrict__ pairs, float* __restrict__ logits) {
    __shared__ float shm[4], shs[4];
    __shared__ float shMS[2];
    int tid = threadIdx.x, wave = tid >> 6, lane = tid & 63;
    float m = -INFINITY, s = 0.f;
    for (int i = tid; i < LOGITS_BLOCKS; i += 256) {
        float2 pr = pairs[i];
        lse_merge(m, s, pr.x, pr.y);
    }
    #pragma unroll
    for (int off = 32; off; off >>= 1) {
        float m2 = __shfl_down(m, off);
        float s2 = __shfl_down(s, off);
        lse_merge(m, s, m2, s2);
    }
    if (lane == 0) { shm[wave] = m; shs[wave] = s; }
    __syncthreads();
    if (tid == 0) {
        float M = shm[0], S = shs[0];
        for (int w = 1; w < 4; ++w) lse_merge(M, S, shm[w], shs[w]);
        shMS[0] = M; shMS[1] = logf(S);
    }
    __syncthreads();
    int v = blockIdx.x * 256 + tid;
    if (v < V) logits[v] = logits[v] - shMS[0] - shMS[1];
}

extern "C" void kernel_launch(void* const* d_in, const int* in_sizes, int n_in,
                              void* d_out, int out_size, void* d_ws, size_t ws_size,
                              hipStream_t stream) {
    const int*   y       = (const int*)d_in[0];
    const float* s_prev  = (const float*)d_in[1];
    const float* h_all   = (const float*)d_in[2];
    const float* emb_W   = (const float*)d_in[3];
    const float* align_W = (const float*)d_in[4];
    const float* align_b = (const float*)d_in[5];
    const float* new_W   = (const float*)d_in[6];
    const float* new_b   = (const float*)d_in[7];
    const float* W_ih    = (const float*)d_in[8];
    const float* b_ih    = (const float*)d_in[9];
    const float* W_hh    = (const float*)d_in[10];
    const float* b_hh    = (const float*)d_in[11];
    const float* out_W   = (const float*)d_in[12];
    const float* out_b   = (const float*)d_in[13];

    float* out      = (float*)d_out;
    float* logp_out = out;            // V
    float* h_out    = out + V;        // H
    float* a_out    = out + V + H;    // L

    // workspace layout (floats):
    //   p[4096] | pairs1 float2[256] | cpart[256*1024] | c[1024] | x[1024]
    //   | h[1024] | pairs2 float2[LOGITS_BLOCKS]
    float*  ws      = (float*)d_ws;
    float*  ws_p    = ws;                               // 4096
    float2* ws_pr1  = (float2*)(ws + 4096);             // 256 pairs (512 floats)
    float*  ws_cp   = ws + 4096 + 512;                  // 262144
    float*  ws_c    = ws_cp + (size_t)NB_ATTN * H;      // 1024
    float*  ws_x    = ws_c + H;                         // 1024
    float*  ws_h    = ws_x + H;                         // 1024
    float2* ws_pr2  = (float2*)(ws_h + H);              // LOGITS_BLOCKS pairs

    k_attn  <<<NB_ATTN, 1024, 0, stream>>>(h_all, s_prev, align_W, align_b,
                                           ws_p, ws_pr1, ws_cp);
    k_merge <<<NB_ATTN, 1024, 0, stream>>>(ws_pr1, ws_p, ws_cp, a_out, ws_c);
    k_xvec  <<<H / 4, 256, 0, stream>>>(new_W, new_b, emb_W, y, ws_c, ws_x);
    k_gru   <<<H, 384, 0, stream>>>(W_ih, b_ih, W_hh, b_hh, ws_x, s_prev, ws_h, h_out);
    k_logits<<<LOGITS_BLOCKS, 256, 0, stream>>>(out_W, out_b, ws_h, logp_out, ws_pr2);
    k_final <<<(V + 255) / 256, 256, 0, stream>>>(ws_pr2, logp_out);
}

// Round 3
// 419.122 us; speedup vs baseline: 1.0571x; 1.0461x over previous
//
#include <hip/hip_runtime.h>
#include <math.h>

#define H 1024
#define V 50257
#define L 4096
#define NB_ATTN 256                       // L / 16 rows per attn block
#define ROWS_PER_LOGB 32                  // 4 waves * 8 rows
#define LOGITS_BLOCKS ((V + ROWS_PER_LOGB - 1) / ROWS_PER_LOGB)   // 1571

// clang-native float4 for __builtin_nontemporal_load (HIP_vector_type rejected)
typedef float float4_nt __attribute__((ext_vector_type(4)));

__device__ __forceinline__ float4_nt nt_load4(const float* p) {
    return __builtin_nontemporal_load((const float4_nt*)p);
}

__device__ __forceinline__ float wave_sum(float v) {
    #pragma unroll
    for (int off = 32; off; off >>= 1) v += __shfl_down(v, off);
    return v;
}

// online log-sum-exp merge: (m,s) <- merge((m,s),(m2,s2)), guarded for -inf
__device__ __forceinline__ void lse_merge(float& m, float& s, float m2, float s2) {
    if (m2 == -INFINITY) return;
    if (m == -INFINITY) { m = m2; s = s2; return; }
    float nm = fmaxf(m, m2);
    s = s * expf(m - nm) + s2 * expf(m2 - nm);
    m = nm;
}

// 1) fused scores + block-local softmax + context partials.
//    Block b owns rows [16b, 16b+16). Wave w computes e for row 16b+w.
//    Then block-local m_b, p = exp(e - m_b), s_b; column-partial
//    cpart[b][j] = sum_l p_l * h_all[l][j] (rows are L2-hot from phase A).
__global__ __launch_bounds__(1024) void k_attn(
    const float* __restrict__ h_all, const float* __restrict__ s_prev,
    const float* __restrict__ align_W, const float* __restrict__ align_b,
    float* __restrict__ p_ws, float2* __restrict__ pairs,
    float* __restrict__ cpart) {
    __shared__ float sh_e[16];
    __shared__ float sh_p[16];
    int tid = threadIdx.x, wave = tid >> 6, lane = tid & 63;
    int b = blockIdx.x;
    int l = b * 16 + wave;
    const float* hrow = h_all + (size_t)l * H;
    const float* Wh = align_W;
    const float* Ws = align_W + H;
    float acc = 0.f;
    #pragma unroll
    for (int it = 0; it < 4; ++it) {
        int k = it * 256 + lane * 4;
        float4 h4 = *(const float4*)(hrow + k);
        float4 w4 = *(const float4*)(Wh + k);
        float4 s4 = *(const float4*)(s_prev + k);
        float4 v4 = *(const float4*)(Ws + k);
        acc += h4.x * w4.x + h4.y * w4.y + h4.z * w4.z + h4.w * w4.w;
        acc += s4.x * v4.x + s4.y * v4.y + s4.z * v4.z + s4.w * v4.w;
    }
    acc = wave_sum(acc);
    if (lane == 0) sh_e[wave] = acc + align_b[0];
    __syncthreads();
    float m_b = sh_e[0];
    #pragma unroll
    for (int i = 1; i < 16; ++i) m_b = fmaxf(m_b, sh_e[i]);
    if (tid < 16) {
        float p = expf(sh_e[tid] - m_b);
        sh_p[tid] = p;
        p_ws[b * 16 + tid] = p;
    }
    __syncthreads();
    if (tid == 0) {
        float s_b = 0.f;
        #pragma unroll
        for (int i = 0; i < 16; ++i) s_b += sh_p[i];
        pairs[b] = make_float2(m_b, s_b);
    }
    // per-column context partial: thread j = tid (coalesced, rows L2-hot)
    float cacc = 0.f;
    #pragma unroll
    for (int i = 0; i < 16; ++i)
        cacc += sh_p[i] * h_all[(size_t)(b * 16 + i) * H + tid];
    cpart[(size_t)b * H + tid] = cacc;
}

// 2) merge: global (M,S) from 256 pairs (redundant per block, L2-hot);
//    write a slice; reduce cpart columns -> c.
//    64 blocks; block b owns cols [16b,16b+16) and a-rows [64b,64b+64).
//    Coalesced cpart reads: 16 consecutive lanes span 16 consecutive cols
//    (64-B contiguous segments vs the old 4-B/64-B-line gather).
__global__ __launch_bounds__(1024) void k_merge(
    const float2* __restrict__ pairs, const float* __restrict__ p_ws,
    const float* __restrict__ cpart, float* __restrict__ a_out,
    float* __restrict__ c) {
    __shared__ float shm[16], shs[16];
    __shared__ float shMS[2];
    __shared__ float shc[64][16];
    int tid = threadIdx.x, wave = tid >> 6, lane = tid & 63;
    float m = -INFINITY, s = 0.f;
    if (tid < NB_ATTN) { float2 pr = pairs[tid]; m = pr.x; s = pr.y; }
    #pragma unroll
    for (int off = 32; off; off >>= 1) {
        float m2 = __shfl_down(m, off);
        float s2 = __shfl_down(s, off);
        lse_merge(m, s, m2, s2);
    }
    if (lane == 0) { shm[wave] = m; shs[wave] = s; }
    __syncthreads();
    if (tid == 0) {
        float M = shm[0], S = shs[0];
        for (int w = 1; w < 16; ++w) lse_merge(M, S, shm[w], shs[w]);
        shMS[0] = M; shMS[1] = S;
    }
    __syncthreads();
    float M = shMS[0];
    float invS = 1.f / shMS[1];
    // attention-weight output: 64 rows per block
    if (tid < 64) {
        int l = blockIdx.x * 64 + tid;
        a_out[l] = p_ws[l] * (expf(pairs[l >> 4].x - M) * invS);
    }
    // c columns: col = 16*b + (tid&15), rows r0 + 64p, p = 0..3
    int cl = tid & 15;
    int r0 = tid >> 4;           // 0..63
    int col = blockIdx.x * 16 + cl;
    float acc = 0.f;
    #pragma unroll
    for (int p = 0; p < 4; ++p) {
        int r = r0 + 64 * p;
        acc += expf(pairs[r].x - M) * cpart[(size_t)r * H + col];
    }
    shc[r0][cl] = acc;
    __syncthreads();
    if (tid < 16) {
        float sum = 0.f;
        #pragma unroll
        for (int i = 0; i < 64; ++i) sum += shc[i][tid];
        c[blockIdx.x * 16 + tid] = sum * invS;
    }
}

// 3) x[i] = new_W[i,:] · [emb ‖ c] + new_b[i]   (wave per row, dot over 2048)
__global__ void k_xvec(const float* __restrict__ new_W, const float* __restrict__ new_b,
                       const float* __restrict__ emb_W, const int* __restrict__ y,
                       const float* __restrict__ c, float* __restrict__ x) {
    int wave = threadIdx.x >> 6, lane = threadIdx.x & 63;
    int i = blockIdx.x * 4 + wave;
    const float* row = new_W + (size_t)i * (2 * H);
    const float* emb = emb_W + (size_t)y[0] * H;
    float acc = 0.f;
    #pragma unroll
    for (int it = 0; it < 8; ++it) {
        int k = it * 256 + lane * 4;
        float4_nt w4 = nt_load4(row + k);
        float4 v4 = (k < H) ? *(const float4*)(emb + k) : *(const float4*)(c + (k - H));
        acc += w4.x * v4.x + w4.y * v4.y + w4.z * v4.z + w4.w * v4.w;
    }
    acc = wave_sum(acc);
    if (lane == 0) x[i] = acc + new_b[i];
}

// 4) fused GRU: block per output i, 6 waves = 6 row-dots, thread 0 applies gates
__global__ void k_gru(const float* __restrict__ W_ih, const float* __restrict__ b_ih,
                      const float* __restrict__ W_hh, const float* __restrict__ b_hh,
                      const float* __restrict__ x, const float* __restrict__ s_prev,
                      float* __restrict__ h_ws, float* __restrict__ h_out) {
    __shared__ float dots[6];
    int wave = threadIdx.x >> 6, lane = threadIdx.x & 63;
    int i = blockIdx.x;
    int g = wave % 3;
    const float* row;
    const float* vec;
    if (wave < 3) { row = W_ih + (size_t)(g * H + i) * H; vec = x; }
    else          { row = W_hh + (size_t)(g * H + i) * H; vec = s_prev; }
    float acc = 0.f;
    #pragma unroll
    for (int it = 0; it < 4; ++it) {
        int k = it * 256 + lane * 4;
        float4_nt w4 = nt_load4(row + k);
        float4 v4 = *(const float4*)(vec + k);
        acc += w4.x * v4.x + w4.y * v4.y + w4.z * v4.z + w4.w * v4.w;
    }
    acc = wave_sum(acc);
    if (lane == 0) dots[wave] = acc;
    __syncthreads();
    if (threadIdx.x == 0) {
        float ir  = dots[0] + b_ih[i];
        float iz  = dots[1] + b_ih[H + i];
        float in_ = dots[2] + b_ih[2 * H + i];
        float hr  = dots[3] + b_hh[i];
        float hz  = dots[4] + b_hh[H + i];
        float hn  = dots[5] + b_hh[2 * H + i];
        float r = 1.f / (1.f + expf(-(ir + hr)));
        float z = 1.f / (1.f + expf(-(iz + hz)));
        float n = tanhf(in_ + r * hn);
        float h = (1.f - z) * n + z * s_prev[i];
        h_ws[i]  = h;
        h_out[i] = h;
    }
}

// 5) logits GEMV: 8 rows per wave, interleaved loads for 8-way MLP;
//    nontemporal out_W stream (read-once, keep L2 for h/logits);
//    per-block online (m,s) pair for LSE
__global__ __launch_bounds__(256, 4) void k_logits(
    const float* __restrict__ out_W, const float* __restrict__ out_b,
    const float* __restrict__ h, float* __restrict__ logits,
    float2* __restrict__ pairs) {
    __shared__ __align__(16) float sh_h[H];
    __shared__ float2 wpair[4];
    int tid = threadIdx.x, wave = tid >> 6, lane = tid & 63;
    ((float4*)sh_h)[tid] = ((const float4*)h)[tid];
    __syncthreads();
    int v0 = blockIdx.x * ROWS_PER_LOGB + wave * 8;
    const float* base = out_W + (size_t)v0 * H;
    float acc[8] = {0.f, 0.f, 0.f, 0.f, 0.f, 0.f, 0.f, 0.f};
    if (v0 + 8 <= V) {
        #pragma unroll
        for (int it = 0; it < 4; ++it) {
            int k = it * 256 + lane * 4;
            float4 h4 = *(const float4*)(sh_h + k);
            #pragma unroll
            for (int r = 0; r < 8; ++r) {
                float4_nt w4 = nt_load4(base + (size_t)r * H + k);
                acc[r] += w4.x * h4.x + w4.y * h4.y + w4.z * h4.z + w4.w * h4.w;
            }
        }
    } else {
        for (int r = 0; r < 8; ++r) {
            if (v0 + r >= V) break;
            const float* rowp = base + (size_t)r * H;
            #pragma unroll
            for (int it = 0; it < 4; ++it) {
                int k = it * 256 + lane * 4;
                float4 h4 = *(const float4*)(sh_h + k);
                float4_nt w4 = nt_load4(rowp + k);
                acc[r] += w4.x * h4.x + w4.y * h4.y + w4.z * h4.z + w4.w * h4.w;
            }
        }
    }
    float m = -INFINITY, s = 0.f;
    #pragma unroll
    for (int r = 0; r < 8; ++r) {
        float red = wave_sum(acc[r]);
        if (lane == 0 && v0 + r < V) {
            float logit = red + out_b[v0 + r];
            logits[v0 + r] = logit;
            lse_merge(m, s, logit, 1.0f);
        }
    }
    if (lane == 0) wpair[wave] = make_float2(m, s);
    __syncthreads();
    if (tid == 0) {
        float M = wpair[0].x, S = wpair[0].y;
        for (int w = 1; w < 4; ++w) lse_merge(M, S, wpair[w].x, wpair[w].y);
        pairs[blockIdx.x] = make_float2(M, S);
    }
}

// 6) fused combine + finalize: each block redundantly reduces all pairs
//    (12.5 KB, L2-hot) then normalizes its 256-logit slice in place.
__global__ void k_final(const float2* __restrict__ pairs, float* __restrict__ logits) {
    __shared__ float shm[4], shs[4];
    __shared__ float shMS[2];
    int tid = threadIdx.x, wave = tid >> 6, lane = tid & 63;
    float m = -INFINITY, s = 0.f;
    for (int i = tid; i < LOGITS_BLOCKS; i += 256) {
        float2 pr = pairs[i];
        lse_merge(m, s, pr.x, pr.y);
    }
    #pragma unroll
    for (int off = 32; off; off >>= 1) {
        float m2 = __shfl_down(m, off);
        float s2 = __shfl_down(s, off);
        lse_merge(m, s, m2, s2);
    }
    if (lane == 0) { shm[wave] = m; shs[wave] = s; }
    __syncthreads();
    if (tid == 0) {
        float M = shm[0], S = shs[0];
        for (int w = 1; w < 4; ++w) lse_merge(M, S, shm[w], shs[w]);
        shMS[0] = M; shMS[1] = logf(S);
    }
    __syncthreads();
    int v = blockIdx.x * 256 + tid;
    if (v < V) logits[v] = logits[v] - shMS[0] - shMS[1];
}

extern "C" void kernel_launch(void* const* d_in, const int* in_sizes, int n_in,
                              void* d_out, int out_size, void* d_ws, size_t ws_size,
                              hipStream_t stream) {
    const int*   y       = (const int*)d_in[0];
    const float* s_prev  = (const float*)d_in[1];
    const float* h_all   = (const float*)d_in[2];
    const float* emb_W   = (const float*)d_in[3];
    const float* align_W = (const float*)d_in[4];
    const float* align_b = (const float*)d_in[5];
    const float* new_W   = (const float*)d_in[6];
    const float* new_b   = (const float*)d_in[7];
    const float* W_ih    = (const float*)d_in[8];
    const float* b_ih    = (const float*)d_in[9];
    const float* W_hh    = (const float*)d_in[10];
    const float* b_hh    = (const float*)d_in[11];
    const float* out_W   = (const float*)d_in[12];
    const float* out_b   = (const float*)d_in[13];

    float* out      = (float*)d_out;
    float* logp_out = out;            // V
    float* h_out    = out + V;        // H
    float* a_out    = out + V + H;    // L

    // workspace layout (floats):
    //   p[4096] | pairs1 float2[256] | cpart[256*1024] | c[1024] | x[1024]
    //   | h[1024] | pairs2 float2[LOGITS_BLOCKS]
    float*  ws      = (float*)d_ws;
    float*  ws_p    = ws;                               // 4096
    float2* ws_pr1  = (float2*)(ws + 4096);             // 256 pairs (512 floats)
    float*  ws_cp   = ws + 4096 + 512;                  // 262144
    float*  ws_c    = ws_cp + (size_t)NB_ATTN * H;      // 1024
    float*  ws_x    = ws_c + H;                         // 1024
    float*  ws_h    = ws_x + H;                         // 1024
    float2* ws_pr2  = (float2*)(ws_h + H);              // LOGITS_BLOCKS pairs

    k_attn  <<<NB_ATTN, 1024, 0, stream>>>(h_all, s_prev, align_W, align_b,
                                           ws_p, ws_pr1, ws_cp);
    k_merge <<<64, 1024, 0, stream>>>(ws_pr1, ws_p, ws_cp, a_out, ws_c);
    k_xvec  <<<H / 4, 256, 0, stream>>>(new_W, new_b, emb_W, y, ws_c, ws_x);
    k_gru   <<<H, 384, 0, stream>>>(W_ih, b_ih, W_hh, b_hh, ws_x, s_prev, ws_h, h_out);
    k_logits<<<LOGITS_BLOCKS, 256, 0, stream>>>(out_W, out_b, ws_h, logp_out, ws_pr2);
    k_final <<<(V + 255) / 256, 256, 0, stream>>>(ws_pr2, logp_out);
}